// Round 4
// baseline (405.767 us; speedup 1.0000x reference)
//
#include <hip/hip_runtime.h>
#include <stdint.h>
#include <stddef.h>

#define M_DIM 8192
#define N_DIM 4096
#define K_DIM 4096

#define BM 128
#define BN 128
#define BK 128   // int8: 128 rows x 128 bytes = 16 KiB per operand tile

typedef int i32x4  __attribute__((ext_vector_type(4)));
typedef int i32x16 __attribute__((ext_vector_type(16)));

__device__ __forceinline__ void async_load16(void* lds, const void* g) {
  __builtin_amdgcn_global_load_lds(
      (const __attribute__((address_space(1))) void*)g,
      (__attribute__((address_space(3))) void*)lds,
      16, 0, 0);
}

// Per-token (row) symmetric int8 quantization of x. UNCHANGED (control).
__global__ void quant_x_kernel(const float* __restrict__ x,
                               signed char* __restrict__ xq,
                               float* __restrict__ xs) {
  const int row = blockIdx.x;
  const float4* xr = (const float4*)(x + (size_t)row * K_DIM);
  const int t = threadIdx.x;
  float4 v[4];
  float m = 0.f;
#pragma unroll
  for (int r = 0; r < 4; ++r) {
    v[r] = xr[r * 256 + t];                       // coalesced 16B/lane
    m = fmaxf(m, fmaxf(fmaxf(fabsf(v[r].x), fabsf(v[r].y)),
                       fmaxf(fabsf(v[r].z), fabsf(v[r].w))));
  }
#pragma unroll
  for (int off = 32; off > 0; off >>= 1)
    m = fmaxf(m, __shfl_down(m, off, 64));
  __shared__ float wmax[4];
  if ((t & 63) == 0) wmax[t >> 6] = m;
  __syncthreads();
  float rowmax = fmaxf(fmaxf(wmax[0], wmax[1]), fmaxf(wmax[2], wmax[3]));
  float inv = rowmax > 0.f ? 127.0f / rowmax : 0.f;
  if (t == 0) xs[row] = rowmax > 0.f ? rowmax * (1.0f / 127.0f) : 0.f;
  uint* oq = (uint*)(xq + (size_t)row * K_DIM);
#pragma unroll
  for (int r = 0; r < 4; ++r) {
    union { signed char c[4]; uint u; } o;
    o.c[0] = (signed char)(int)rintf(v[r].x * inv);
    o.c[1] = (signed char)(int)rintf(v[r].y * inv);
    o.c[2] = (signed char)(int)rintf(v[r].z * inv);
    o.c[3] = (signed char)(int)rintf(v[r].w * inv);
    oq[r * 256 + t] = o.u;                        // coalesced 4B/lane
  }
}

// W int32 [-127,127] -> int8 (exact pack). UNCHANGED (control).
__global__ void pack_w_kernel(const int* __restrict__ w, signed char* __restrict__ wp) {
  const int4* wi = (const int4*)w;
  uint* wo = (uint*)wp;
  size_t base = (size_t)blockIdx.x * 1024 + threadIdx.x;   // int4-chunk index
#pragma unroll
  for (int r = 0; r < 4; ++r) {
    int4 a = wi[base + r * 256];
    union { signed char c[4]; uint u; } o;
    o.c[0] = (signed char)a.x; o.c[1] = (signed char)a.y;
    o.c[2] = (signed char)a.z; o.c[3] = (signed char)a.w;
    wo[base + r * 256] = o.u;
  }
}

// C[M,N] = sum_k Aq[m,k]*Bq[n,k] * xs[m] * scaler[n].
// R8: back to the R0 single-buffer 2-barrier shell (3 blocks/CU — the
// dbuf experiment showed occupancy 35%->21% and MfmaUtil 43->36%, net
// regression; implicit multi-block overlap beats explicit dbuf here).
// Changed: MFMA shape 16x16x64 -> 32x32x32 i8 (4404 vs 3944 TOPS ubench,
// half the instruction count, same per-lane 16B chunk reads from LDS).
// A/B frag: row = lane&31, k = (lane>>5)*16 + j  (16 consecutive int8 =
// one swizzled 16B chunk; extrapolated exactly like the verified 16x16
// map). C/D: col = lane&31, row = (reg&3)+8*(reg>>2)+4*(lane>>5)
// (m74/m101-verified, dtype-independent). Wrong map => absmax explosion.
__global__ __launch_bounds__(256, 2) void gemm_i8(
    const signed char* __restrict__ Aq, const signed char* __restrict__ Bq,
    const float* __restrict__ xs, const float* __restrict__ scaler,
    float* __restrict__ C) {
  __shared__ __align__(16) uint8_t sA[BM * BK];  // 16 KiB
  __shared__ __align__(16) uint8_t sB[BN * BK];  // 16 KiB

  // XCD-grouped mapping (neutral, keeps B slabs L2-resident).
  const int bid  = blockIdx.x;
  const int xcd  = bid & 7;
  const int slot = bid >> 3;
  const int tile_n = (xcd * 4 + (slot & 3)) * BN;
  const int tile_m = (slot >> 2) * BM;

  const int w    = threadIdx.x >> 6;
  const int lane = threadIdx.x & 63;
  const int hi   = lane >> 5;        // k-half selector for 32x32 frags
  const int r32  = lane & 31;        // row within a 32-block
  const int wrow = (w >> 1) * 64;
  const int wcol = (w & 1) * 64;

  i32x16 acc[2][2];
#pragma unroll
  for (int i = 0; i < 2; ++i)
#pragma unroll
    for (int j = 0; j < 2; ++j)
#pragma unroll
      for (int r = 0; r < 16; ++r)
        acc[i][j][r] = 0;

  for (int kt = 0; kt < K_DIM; kt += BK) {
    // Stage A and B: 1024 16B-chunks each, 4 rounds x 4 waves x 64 lanes.
    // Slot g holds (r = g>>3, c = (g&7) ^ (r&7)); lds addr = wave-uniform
    // base + lane*16 (global_load_lds constraint). 0 conflicts measured.
#pragma unroll
    for (int p = 0; p < 4; ++p) {
      int g = ((p * 4 + w) << 6) + lane;
      int r = g >> 3;
      int c = (g & 7) ^ (r & 7);
      async_load16(sA + (size_t)g * 16,
                   Aq + (size_t)(tile_m + r) * K_DIM + kt + c * 16);
    }
#pragma unroll
    for (int p = 0; p < 4; ++p) {
      int g = ((p * 4 + w) << 6) + lane;
      int r = g >> 3;
      int c = (g & 7) ^ (r & 7);
      async_load16(sB + (size_t)g * 16,
                   Bq + (size_t)(tile_n + r) * K_DIM + kt + c * 16);
    }
    __syncthreads();

    // 4 K-windows of 32; per window: 4 ds_read_b128 + 4 MFMA 32x32x32.
#pragma unroll
    for (int kw = 0; kw < 4; ++kw) {
      const int ck = 2 * kw + hi;    // 16B chunk holding k=[kw*32+hi*16,+16)
      i32x4 af[2], bf[2];
#pragma unroll
      for (int t = 0; t < 2; ++t) {
        int ra = wrow + t * 32 + r32;
        af[t] = *(const i32x4*)(sA + (size_t)(((ra << 3) + (ck ^ (ra & 7))) << 4));
        int rb = wcol + t * 32 + r32;
        bf[t] = *(const i32x4*)(sB + (size_t)(((rb << 3) + (ck ^ (rb & 7))) << 4));
      }
#pragma unroll
      for (int i = 0; i < 2; ++i)
#pragma unroll
        for (int j = 0; j < 2; ++j)
          acc[i][j] = __builtin_amdgcn_mfma_i32_32x32x32_i8(
              af[i], bf[j], acc[i][j], 0, 0, 0);
    }
    __syncthreads();
  }

  // Epilogue: 32x32 C/D layout col=lane&31, row=(reg&3)+8*(reg>>2)+4*hi.
  const int hi4 = 4 * hi;
#pragma unroll
  for (int i = 0; i < 2; ++i) {
    const int rbase = tile_m + wrow + i * 32 + hi4;
    float rsv[16];
#pragma unroll
    for (int r = 0; r < 16; ++r)
      rsv[r] = xs[rbase + (r & 3) + 8 * (r >> 2)];
#pragma unroll
    for (int j = 0; j < 2; ++j) {
      int col = tile_n + wcol + j * 32 + r32;
      float s = scaler[col];
#pragma unroll
      for (int r = 0; r < 16; ++r) {
        int row = rbase + (r & 3) + 8 * (r >> 2);
        C[(size_t)row * N_DIM + col] = (float)acc[i][j][r] * rsv[r] * s;
      }
    }
  }
}

// Correct-but-slow insurance if ws_size is too small.
__global__ void fallback_kernel(const float* __restrict__ x,
                                const int* __restrict__ wq,
                                const float* __restrict__ s,
                                float* __restrict__ out) {
  size_t idx = (size_t)blockIdx.x * blockDim.x + threadIdx.x;
  int m = (int)(idx / N_DIM), n = (int)(idx % N_DIM);
  const float* xr = x + (size_t)m * K_DIM;
  const int* wr = wq + (size_t)n * K_DIM;
  float acc = 0.f;
  for (int k = 0; k < K_DIM; ++k) acc += xr[k] * (float)wr[k];
  out[idx] = acc * s[n];
}

extern "C" void kernel_launch(void* const* d_in, const int* in_sizes, int n_in,
                              void* d_out, int out_size, void* d_ws, size_t ws_size,
                              hipStream_t stream) {
  const float* x = (const float*)d_in[0];
  const int* wq = (const int*)d_in[1];   // int32 (verified R2)
  const float* sc = (const float*)d_in[2];
  float* out = (float*)d_out;

  const size_t nx = (size_t)M_DIM * K_DIM;   // 33,554,432
  const size_t nw = (size_t)N_DIM * K_DIM;   // 16,777,216
  const size_t off_xq = 32768;               // xs: 8192 floats
  const size_t off_wp = off_xq + nx;
  const size_t need = off_wp + nw;           // ~50.4 MB

  if (ws_size < need) {
    size_t total = (size_t)M_DIM * N_DIM;
    fallback_kernel<<<(int)(total / 256), 256, 0, stream>>>(x, wq, sc, out);
    return;
  }

  float* xs = (float*)d_ws;
  signed char* xq = (signed char*)d_ws + off_xq;
  signed char* wp = (signed char*)d_ws + off_wp;

  quant_x_kernel<<<M_DIM, 256, 0, stream>>>(x, xq, xs);
  // nw/4 int4-chunks, 1024 chunks per block -> 4096 blocks.
  pack_w_kernel<<<(int)(nw / 4 / 1024), 256, 0, stream>>>(wq, wp);

  gemm_i8<<<(N_DIM / BN) * (M_DIM / BM), 256, 0, stream>>>(xq, wp, xs, sc, out);
}

// Round 5
// 405.141 us; speedup vs baseline: 1.0015x; 1.0015x over previous
//
#include <hip/hip_runtime.h>
#include <stdint.h>
#include <stddef.h>

#define M_DIM 8192
#define N_DIM 4096
#define K_DIM 4096

#define BM 128
#define BN 128
#define BK 128   // int8: 128 rows x 128 bytes = 16 KiB per operand tile

typedef int i32x4  __attribute__((ext_vector_type(4)));
typedef int i32x16 __attribute__((ext_vector_type(16)));

__device__ __forceinline__ void async_load16(void* lds, const void* g) {
  __builtin_amdgcn_global_load_lds(
      (const __attribute__((address_space(1))) void*)g,
      (__attribute__((address_space(3))) void*)lds,
      16, 0, 0);
}

// Per-token (row) symmetric int8 quantization of x. UNCHANGED (control).
__global__ void quant_x_kernel(const float* __restrict__ x,
                               signed char* __restrict__ xq,
                               float* __restrict__ xs) {
  const int row = blockIdx.x;
  const float4* xr = (const float4*)(x + (size_t)row * K_DIM);
  const int t = threadIdx.x;
  float4 v[4];
  float m = 0.f;
#pragma unroll
  for (int r = 0; r < 4; ++r) {
    v[r] = xr[r * 256 + t];                       // coalesced 16B/lane
    m = fmaxf(m, fmaxf(fmaxf(fabsf(v[r].x), fabsf(v[r].y)),
                       fmaxf(fabsf(v[r].z), fabsf(v[r].w))));
  }
#pragma unroll
  for (int off = 32; off > 0; off >>= 1)
    m = fmaxf(m, __shfl_down(m, off, 64));
  __shared__ float wmax[4];
  if ((t & 63) == 0) wmax[t >> 6] = m;
  __syncthreads();
  float rowmax = fmaxf(fmaxf(wmax[0], wmax[1]), fmaxf(wmax[2], wmax[3]));
  float inv = rowmax > 0.f ? 127.0f / rowmax : 0.f;
  if (t == 0) xs[row] = rowmax > 0.f ? rowmax * (1.0f / 127.0f) : 0.f;
  uint* oq = (uint*)(xq + (size_t)row * K_DIM);
#pragma unroll
  for (int r = 0; r < 4; ++r) {
    union { signed char c[4]; uint u; } o;
    o.c[0] = (signed char)(int)rintf(v[r].x * inv);
    o.c[1] = (signed char)(int)rintf(v[r].y * inv);
    o.c[2] = (signed char)(int)rintf(v[r].z * inv);
    o.c[3] = (signed char)(int)rintf(v[r].w * inv);
    oq[r * 256 + t] = o.u;                        // coalesced 4B/lane
  }
}

// W int32 [-127,127] -> int8 (exact pack). UNCHANGED (control).
__global__ void pack_w_kernel(const int* __restrict__ w, signed char* __restrict__ wp) {
  const int4* wi = (const int4*)w;
  uint* wo = (uint*)wp;
  size_t base = (size_t)blockIdx.x * 1024 + threadIdx.x;   // int4-chunk index
#pragma unroll
  for (int r = 0; r < 4; ++r) {
    int4 a = wi[base + r * 256];
    union { signed char c[4]; uint u; } o;
    o.c[0] = (signed char)a.x; o.c[1] = (signed char)a.y;
    o.c[2] = (signed char)a.z; o.c[3] = (signed char)a.w;
    wo[base + r * 256] = o.u;
  }
}

// C[M,N] = sum_k Aq[m,k]*Bq[n,k] * xs[m] * scaler[n].
// R9: 32x32x32 i8 MFMA (R4) + conflict-free swizzle.
// R4 measured 1.678e7 bank-conflict cycles: with swz = ck^(row&7), a
// 32-lane half reads 32 rows at ONE chunk, so rows {x,x+8,x+16,x+24}
// share swz -> same bank-set (byte%128) -> 4-way serialization (rows
// contribute 0 to bank: 128B row stride = exactly 32 banks). The 16x16
// variant only ever had 2-way sets {l,l+8} (free, m136) = measured 0.
// Fix: swz = ck ^ (row&7) ^ 2*((row>>4)&1) -> {l,l+16} now differ in
// swz bit 1; remaining sets are 2-way {l,l+8} (free). Applied on BOTH
// the staging source permutation and the read address (rule #21).
__global__ __launch_bounds__(256, 2) void gemm_i8(
    const signed char* __restrict__ Aq, const signed char* __restrict__ Bq,
    const float* __restrict__ xs, const float* __restrict__ scaler,
    float* __restrict__ C) {
  __shared__ __align__(16) uint8_t sA[BM * BK];  // 16 KiB
  __shared__ __align__(16) uint8_t sB[BN * BK];  // 16 KiB

  // XCD-grouped mapping (neutral, keeps B slabs L2-resident).
  const int bid  = blockIdx.x;
  const int xcd  = bid & 7;
  const int slot = bid >> 3;
  const int tile_n = (xcd * 4 + (slot & 3)) * BN;
  const int tile_m = (slot >> 2) * BM;

  const int w    = threadIdx.x >> 6;
  const int lane = threadIdx.x & 63;
  const int hi   = lane >> 5;        // k-half selector for 32x32 frags
  const int r32  = lane & 31;        // row within a 32-block
  const int wrow = (w >> 1) * 64;
  const int wcol = (w & 1) * 64;

  i32x16 acc[2][2];
#pragma unroll
  for (int i = 0; i < 2; ++i)
#pragma unroll
    for (int j = 0; j < 2; ++j)
#pragma unroll
      for (int r = 0; r < 16; ++r)
        acc[i][j][r] = 0;

  for (int kt = 0; kt < K_DIM; kt += BK) {
    // Stage A and B: 1024 16B-chunks each, 4 rounds x 4 waves x 64 lanes.
    // Slot g holds row r = g>>3, chunk c = (g&7) ^ (r&7) ^ 2*((r>>4)&1);
    // lds addr = wave-uniform base + lane*16 (global_load_lds constraint).
    // 8 consecutive lanes still cover one contiguous 128B global row.
#pragma unroll
    for (int p = 0; p < 4; ++p) {
      int g = ((p * 4 + w) << 6) + lane;
      int r = g >> 3;
      int c = (g & 7) ^ (r & 7) ^ (2 * ((r >> 4) & 1));
      async_load16(sA + (size_t)g * 16,
                   Aq + (size_t)(tile_m + r) * K_DIM + kt + c * 16);
    }
#pragma unroll
    for (int p = 0; p < 4; ++p) {
      int g = ((p * 4 + w) << 6) + lane;
      int r = g >> 3;
      int c = (g & 7) ^ (r & 7) ^ (2 * ((r >> 4) & 1));
      async_load16(sB + (size_t)g * 16,
                   Bq + (size_t)(tile_n + r) * K_DIM + kt + c * 16);
    }
    __syncthreads();

    // 4 K-windows of 32; per window: 4 ds_read_b128 + 4 MFMA 32x32x32.
#pragma unroll
    for (int kw = 0; kw < 4; ++kw) {
      const int ck = 2 * kw + hi;    // 16B chunk holding k=[kw*32+hi*16,+16)
      i32x4 af[2], bf[2];
#pragma unroll
      for (int t = 0; t < 2; ++t) {
        int ra = wrow + t * 32 + r32;
        int sa = ck ^ (ra & 7) ^ (2 * ((ra >> 4) & 1));
        af[t] = *(const i32x4*)(sA + (size_t)(((ra << 3) + sa) << 4));
        int rb = wcol + t * 32 + r32;
        int sb = ck ^ (rb & 7) ^ (2 * ((rb >> 4) & 1));
        bf[t] = *(const i32x4*)(sB + (size_t)(((rb << 3) + sb) << 4));
      }
#pragma unroll
      for (int i = 0; i < 2; ++i)
#pragma unroll
        for (int j = 0; j < 2; ++j)
          acc[i][j] = __builtin_amdgcn_mfma_i32_32x32x32_i8(
              af[i], bf[j], acc[i][j], 0, 0, 0);
    }
    __syncthreads();
  }

  // Epilogue: 32x32 C/D layout col=lane&31, row=(reg&3)+8*(reg>>2)+4*hi.
  const int hi4 = 4 * hi;
#pragma unroll
  for (int i = 0; i < 2; ++i) {
    const int rbase = tile_m + wrow + i * 32 + hi4;
    float rsv[16];
#pragma unroll
    for (int r = 0; r < 16; ++r)
      rsv[r] = xs[rbase + (r & 3) + 8 * (r >> 2)];
#pragma unroll
    for (int j = 0; j < 2; ++j) {
      int col = tile_n + wcol + j * 32 + r32;
      float s = scaler[col];
#pragma unroll
      for (int r = 0; r < 16; ++r) {
        int row = rbase + (r & 3) + 8 * (r >> 2);
        C[(size_t)row * N_DIM + col] = (float)acc[i][j][r] * rsv[r] * s;
      }
    }
  }
}

// Correct-but-slow insurance if ws_size is too small.
__global__ void fallback_kernel(const float* __restrict__ x,
                                const int* __restrict__ wq,
                                const float* __restrict__ s,
                                float* __restrict__ out) {
  size_t idx = (size_t)blockIdx.x * blockDim.x + threadIdx.x;
  int m = (int)(idx / N_DIM), n = (int)(idx % N_DIM);
  const float* xr = x + (size_t)m * K_DIM;
  const int* wr = wq + (size_t)n * K_DIM;
  float acc = 0.f;
  for (int k = 0; k < K_DIM; ++k) acc += xr[k] * (float)wr[k];
  out[idx] = acc * s[n];
}

extern "C" void kernel_launch(void* const* d_in, const int* in_sizes, int n_in,
                              void* d_out, int out_size, void* d_ws, size_t ws_size,
                              hipStream_t stream) {
  const float* x = (const float*)d_in[0];
  const int* wq = (const int*)d_in[1];   // int32 (verified R2)
  const float* sc = (const float*)d_in[2];
  float* out = (float*)d_out;

  const size_t nx = (size_t)M_DIM * K_DIM;   // 33,554,432
  const size_t nw = (size_t)N_DIM * K_DIM;   // 16,777,216
  const size_t off_xq = 32768;               // xs: 8192 floats
  const size_t off_wp = off_xq + nx;
  const size_t need = off_wp + nw;           // ~50.4 MB

  if (ws_size < need) {
    size_t total = (size_t)M_DIM * N_DIM;
    fallback_kernel<<<(int)(total / 256), 256, 0, stream>>>(x, wq, sc, out);
    return;
  }

  float* xs = (float*)d_ws;
  signed char* xq = (signed char*)d_ws + off_xq;
  signed char* wp = (signed char*)d_ws + off_wp;

  quant_x_kernel<<<M_DIM, 256, 0, stream>>>(x, xq, xs);
  // nw/4 int4-chunks, 1024 chunks per block -> 4096 blocks.
  pack_w_kernel<<<(int)(nw / 4 / 1024), 256, 0, stream>>>(wq, wp);

  gemm_i8<<<(N_DIM / BN) * (M_DIM / BM), 256, 0, stream>>>(xq, wp, xs, sc, out);
}

// Round 6
// 383.560 us; speedup vs baseline: 1.0579x; 1.0563x over previous
//
#include <hip/hip_runtime.h>
#include <stdint.h>
#include <stddef.h>

#define M_DIM 8192
#define N_DIM 4096
#define K_DIM 4096

#define BM 128
#define BN 128
#define BK 128   // int8: 128 rows x 128 bytes = 16 KiB per operand tile

typedef int i32x4 __attribute__((ext_vector_type(4)));

__device__ __forceinline__ void async_load16(void* lds, const void* g) {
  __builtin_amdgcn_global_load_lds(
      (const __attribute__((address_space(1))) void*)g,
      (__attribute__((address_space(3))) void*)lds,
      16, 0, 0);
}

// R10: quant_x and pack_w fused into ONE dispatch.
// Blocks [0, 8192): per-token symmetric int8 quant of x (one row each).
// Blocks [8192, 12288): int32->int8 exact pack of W (4096 int4-chunks each).
// Fusion saves a launch AND makes combined aux cost visible in the top-5
// profile (it can only appear if it exceeds the gemm's ~140 us — which is
// exactly the hypothesis being tested).
__global__ void fused_aux_kernel(const float* __restrict__ x,
                                 signed char* __restrict__ xq,
                                 float* __restrict__ xs,
                                 const int* __restrict__ w,
                                 signed char* __restrict__ wp) {
  const int t = threadIdx.x;
  if (blockIdx.x < M_DIM) {
    // ---- quant path (unchanged logic from R5's lane-contiguous version) ----
    const int row = blockIdx.x;
    const float4* xr = (const float4*)(x + (size_t)row * K_DIM);
    float4 v[4];
    float m = 0.f;
#pragma unroll
    for (int r = 0; r < 4; ++r) {
      v[r] = xr[r * 256 + t];                       // coalesced 16B/lane
      m = fmaxf(m, fmaxf(fmaxf(fabsf(v[r].x), fabsf(v[r].y)),
                         fmaxf(fabsf(v[r].z), fabsf(v[r].w))));
    }
#pragma unroll
    for (int off = 32; off > 0; off >>= 1)
      m = fmaxf(m, __shfl_down(m, off, 64));
    __shared__ float wmax[4];
    if ((t & 63) == 0) wmax[t >> 6] = m;
    __syncthreads();
    float rowmax = fmaxf(fmaxf(wmax[0], wmax[1]), fmaxf(wmax[2], wmax[3]));
    float inv = rowmax > 0.f ? 127.0f / rowmax : 0.f;
    if (t == 0) xs[row] = rowmax > 0.f ? rowmax * (1.0f / 127.0f) : 0.f;
    uint* oq = (uint*)(xq + (size_t)row * K_DIM);
#pragma unroll
    for (int r = 0; r < 4; ++r) {
      union { signed char c[4]; uint u; } o;
      o.c[0] = (signed char)(int)rintf(v[r].x * inv);
      o.c[1] = (signed char)(int)rintf(v[r].y * inv);
      o.c[2] = (signed char)(int)rintf(v[r].z * inv);
      o.c[3] = (signed char)(int)rintf(v[r].w * inv);
      oq[r * 256 + t] = o.u;                        // coalesced 4B/lane
    }
  } else {
    // ---- pack path (unchanged logic from R5) ----
    const int4* wi = (const int4*)w;
    uint* wo = (uint*)wp;
    size_t base = (size_t)(blockIdx.x - M_DIM) * 1024 + t;   // int4-chunk idx
#pragma unroll
    for (int r = 0; r < 4; ++r) {
      int4 a = wi[base + r * 256];
      union { signed char c[4]; uint u; } o;
      o.c[0] = (signed char)a.x; o.c[1] = (signed char)a.y;
      o.c[2] = (signed char)a.z; o.c[3] = (signed char)a.w;
      wo[base + r * 256] = o.u;
    }
  }
}

// C[M,N] = sum_k Aq[m,k]*Bq[n,k] * xs[m] * scaler[n], int8 MFMA 16x16x64.
// R10: byte-identical revert to the R0 gemm — the best measured variant
// (132.3 us @ R0 clocks, MfmaUtil 48%, 0 bank conflicts). The 32x32x32
// shape (R4/R5) carried a +4 cyc/ds_read conflict penalty whose structure
// survived an XOR swizzle fix (model falsified) — net slower. The dbuf
// variant (R3) lost occupancy (35%->21%). This shell is the proven local
// optimum for the 2-phase structure.
__global__ __launch_bounds__(256, 2) void gemm_i8(
    const signed char* __restrict__ Aq, const signed char* __restrict__ Bq,
    const float* __restrict__ xs, const float* __restrict__ scaler,
    float* __restrict__ C) {
  __shared__ __align__(16) uint8_t sA[BM * BK];  // 16 KiB
  __shared__ __align__(16) uint8_t sB[BN * BK];  // 16 KiB

  // XCD-grouped mapping (neutral, keeps B slabs L2-resident).
  const int bid  = blockIdx.x;
  const int xcd  = bid & 7;
  const int slot = bid >> 3;
  const int tile_n = (xcd * 4 + (slot & 3)) * BN;
  const int tile_m = (slot >> 2) * BM;

  const int w    = threadIdx.x >> 6;
  const int lane = threadIdx.x & 63;
  const int q    = lane >> 4;
  const int m16  = lane & 15;
  const int wrow = (w >> 1) * 64;
  const int wcol = (w & 1) * 64;

  i32x4 acc[4][4];
#pragma unroll
  for (int i = 0; i < 4; ++i)
#pragma unroll
    for (int j = 0; j < 4; ++j)
      acc[i][j] = (i32x4){0, 0, 0, 0};

  for (int kt = 0; kt < K_DIM; kt += BK) {
    // Stage A and B: 1024 16B-chunks each, 4 rounds x 4 waves x 64 lanes.
    // Slot g holds (r = g>>3, c = (g&7) ^ (r&7)); lds addr = wave-uniform
    // base + lane*16 (global_load_lds constraint). 0 conflicts measured.
#pragma unroll
    for (int p = 0; p < 4; ++p) {
      int g = ((p * 4 + w) << 6) + lane;
      int r = g >> 3;
      int c = (g & 7) ^ (r & 7);
      async_load16(sA + (size_t)g * 16,
                   Aq + (size_t)(tile_m + r) * K_DIM + kt + c * 16);
    }
#pragma unroll
    for (int p = 0; p < 4; ++p) {
      int g = ((p * 4 + w) << 6) + lane;
      int r = g >> 3;
      int c = (g & 7) ^ (r & 7);
      async_load16(sB + (size_t)g * 16,
                   Bq + (size_t)(tile_n + r) * K_DIM + kt + c * 16);
    }
    __syncthreads();

#pragma unroll
    for (int ks = 0; ks < 2; ++ks) {
      const int ck = (ks << 2) + q;   // chunk index 0..7 = K bytes [ck*16, +16)
      i32x4 af[4], bfr[4];
#pragma unroll
      for (int t = 0; t < 4; ++t) {
        int ra = wrow + t * 16 + m16;
        af[t] = *(const i32x4*)(sA + (size_t)(((ra << 3) + (ck ^ (ra & 7))) << 4));
        int rb = wcol + t * 16 + m16;
        bfr[t] = *(const i32x4*)(sB + (size_t)(((rb << 3) + (ck ^ (rb & 7))) << 4));
      }
#pragma unroll
      for (int i = 0; i < 4; ++i)
#pragma unroll
        for (int j = 0; j < 4; ++j)
          acc[i][j] = __builtin_amdgcn_mfma_i32_16x16x64_i8(
              af[i], bfr[j], acc[i][j], 0, 0, 0);
    }
    __syncthreads();
  }

  // Epilogue: C/D col=lane&15, row=(lane>>4)*4+reg (verified layout).
  float rs[4][4];
#pragma unroll
  for (int i = 0; i < 4; ++i)
#pragma unroll
    for (int r = 0; r < 4; ++r)
      rs[i][r] = xs[tile_m + wrow + i * 16 + q * 4 + r];
#pragma unroll
  for (int j = 0; j < 4; ++j) {
    int col = tile_n + wcol + j * 16 + m16;
    float s = scaler[col];
#pragma unroll
    for (int i = 0; i < 4; ++i) {
      int row0 = tile_m + wrow + i * 16 + q * 4;
#pragma unroll
      for (int r = 0; r < 4; ++r)
        C[(size_t)(row0 + r) * N_DIM + col] = (float)acc[i][j][r] * rs[i][r] * s;
    }
  }
}

// Correct-but-slow insurance if ws_size is too small.
__global__ void fallback_kernel(const float* __restrict__ x,
                                const int* __restrict__ wq,
                                const float* __restrict__ s,
                                float* __restrict__ out) {
  size_t idx = (size_t)blockIdx.x * blockDim.x + threadIdx.x;
  int m = (int)(idx / N_DIM), n = (int)(idx % N_DIM);
  const float* xr = x + (size_t)m * K_DIM;
  const int* wr = wq + (size_t)n * K_DIM;
  float acc = 0.f;
  for (int k = 0; k < K_DIM; ++k) acc += xr[k] * (float)wr[k];
  out[idx] = acc * s[n];
}

extern "C" void kernel_launch(void* const* d_in, const int* in_sizes, int n_in,
                              void* d_out, int out_size, void* d_ws, size_t ws_size,
                              hipStream_t stream) {
  const float* x = (const float*)d_in[0];
  const int* wq = (const int*)d_in[1];   // int32 (verified R2)
  const float* sc = (const float*)d_in[2];
  float* out = (float*)d_out;

  const size_t nx = (size_t)M_DIM * K_DIM;   // 33,554,432
  const size_t nw = (size_t)N_DIM * K_DIM;   // 16,777,216
  const size_t off_xq = 32768;               // xs: 8192 floats
  const size_t off_wp = off_xq + nx;
  const size_t need = off_wp + nw;           // ~50.4 MB

  if (ws_size < need) {
    size_t total = (size_t)M_DIM * N_DIM;
    fallback_kernel<<<(int)(total / 256), 256, 0, stream>>>(x, wq, sc, out);
    return;
  }

  float* xs = (float*)d_ws;
  signed char* xq = (signed char*)d_ws + off_xq;
  signed char* wp = (signed char*)d_ws + off_wp;

  // One fused aux dispatch: 8192 quant blocks + 4096 pack blocks.
  fused_aux_kernel<<<M_DIM + (int)(nw / 4 / 1024), 256, 0, stream>>>(
      x, xq, xs, wq, wp);

  gemm_i8<<<(N_DIM / BN) * (M_DIM / BM), 256, 0, stream>>>(xq, wp, xs, sc, out);
}